// Round 7
// baseline (220.778 us; speedup 1.0000x reference)
//
#include <hip/hip_runtime.h>
#include <cstdint>

// Problem constants (B,S,H,D from reference)
#define BB 4
#define SS 2048
#define HH 8
#define DD 64
#define CC 64          // chunk length
#define NCK (SS/CC)    // 32 chunks
#define BHH (BB*HH)    // 32

typedef __attribute__((ext_vector_type(8))) short  short8;   // 8 bf16 (MFMA A/B frag)
typedef __attribute__((ext_vector_type(4))) float  f32x4;    // MFMA C/D frag
typedef __attribute__((ext_vector_type(4))) unsigned short us4;
typedef unsigned long long u64;

__device__ __forceinline__ float elu1(float x) {
    return x > 0.f ? x + 1.f : __expf(x);
}
// fp32 -> bf16 RNE
__device__ __forceinline__ unsigned short f2bf(float f) {
    unsigned int u = __float_as_uint(f);
    u += 0x7FFFu + ((u >> 16) & 1u);
    return (unsigned short)(u >> 16);
}
__device__ __forceinline__ float bf2f(unsigned short h) {
    return __uint_as_float(((unsigned int)h) << 16);
}
// XOR swizzle for [64][64] bf16 tiles (rows 128B): spreads 16B units so
// row-varying b128 fragment reads avoid same-bank serialization. Published
// aggregate images use the same swizzled layout (element-wise sums are
// layout-agnostic; col granule is 4 so u64 alignment is preserved).
#define SWZ(r,c) ((r) * DD + ((c) ^ (((r) & 7) << 3)))

// 4x4 lane-transpose across lane groups M0,M1 (4 shfl_xor).
template<int M0, int M1>
__device__ __forceinline__ void xpose4(float v[4], int lane) {
    {
        const bool hi = (lane & M0) != 0;
        float x0 = hi ? v[0] : v[1];
        float x1 = hi ? v[2] : v[3];
        float r0 = __shfl_xor(x0, M0);
        float r1 = __shfl_xor(x1, M0);
        if (hi) { v[0] = r0; v[2] = r1; } else { v[1] = r0; v[3] = r1; }
    }
    {
        const bool hi = (lane & M1) != 0;
        float x0 = hi ? v[0] : v[2];
        float x1 = hi ? v[1] : v[3];
        float r0 = __shfl_xor(x0, M1);
        float r1 = __shfl_xor(x1, M1);
        if (hi) { v[0] = r0; v[1] = r1; } else { v[2] = r0; v[3] = r1; }
    }
}

__device__ __forceinline__ u64 pack4bf(const float v[4]) {
    u64 r;
    r  = (u64)f2bf(v[0]);
    r |= (u64)f2bf(v[1]) << 16;
    r |= (u64)f2bf(v[2]) << 32;
    r |= (u64)f2bf(v[3]) << 48;
    return r;
}

// ---------------------------------------------------------------------------
// Single fused kernel with decoupled lookback (rocPRIM-style single-pass
// chunked scan). Block id = c*BHH + bh (chunk-major: every predecessor of a
// block has a strictly smaller id; command processor dispatches in order, and
// __launch_bounds__(256,4) + 32KB LDS keep all 1024 blocks co-resident).
//  A: stage q,k,v -> qb,kb,K^T,vT (bf16, swizzled LDS); MFMA S_c = V^T K.
//  B: publish S_c image via agent-scope atomic stores (sc1 -> L3-coherent
//     across XCDs and graph replays); release flag. MFMA QK^T meanwhile.
//  C: poll predecessor flags (vector ballot), fp32-sum their aggregate
//     images (<=31 x 32B/thread, pipelined L3 loads) = exclusive prefix.
//  D: overlay S_excl^T and causal-masked scores in LDS; O = Q@S + As@V;
//     out = norm * O.
// Flags: poison 0xAAAAAAAA != 1 counts as "not ready"; ws re-poisoned before
// every launch, so no stale flags across replays.
// ---------------------------------------------------------------------------
__global__ __launch_bounds__(256, 4) void fused_kernel(
    const float* __restrict__ qk, const float* __restrict__ v,
    const float* __restrict__ nrm, const float* __restrict__ offset,
    u64* __restrict__ aggWs, int* __restrict__ flags,
    float* __restrict__ out)
{
    const int blk = blockIdx.x;
    const int c  = blk / BHH;      // chunk index (major => predecessors first)
    const int bh = blk % BHH;
    const int b = bh / HH, h = bh % HH;
    const int s0 = c * CC;

    __shared__ __align__(16) unsigned short qb[CC * DD];   // Q  [s][d]  swz
    __shared__ __align__(16) unsigned short kb[CC * DD];   // K  [s2][d] swz -> As[s][s2]
    __shared__ __align__(16) unsigned short vT[CC * DD];   // V^T[t][s]  swz
    __shared__ __align__(16) unsigned short stk[CC * DD];  // K^T[d][s]  swz -> S_excl^T[t][d]

    const int tid = threadIdx.x, lane = tid & 63;
    const int wid = tid >> 6;

    // ---- A: stage (one pass over q,k,v; 4x4 lane transposes for K^T,V^T) ----
#pragma unroll
    for (int iter = 0; iter < 4; ++iter) {
        const int it = iter * 256 + tid;
        const int r = it >> 4, c0 = (it & 15) * 4;   // row s=r, cols c0..c0+3
        const int g = lane >> 4;                     // row within 4x4 block
        const int rb = r - g;                        // 4-aligned block row base

        const size_t qrow = (((size_t)(b * SS + s0 + r) * 2 + 0) * HH + h) * DD;

        float4 fq = *reinterpret_cast<const float4*>(qk + qrow + c0);
        us4 uq; uq.x = f2bf(elu1(fq.x)); uq.y = f2bf(elu1(fq.y));
                uq.z = f2bf(elu1(fq.z)); uq.w = f2bf(elu1(fq.w));
        *reinterpret_cast<us4*>(&qb[SWZ(r, c0)]) = uq;

        float4 fk = *reinterpret_cast<const float4*>(qk + qrow + (size_t)HH * DD + c0);
        float kv4[4] = { elu1(fk.x) * 0.125f, elu1(fk.y) * 0.125f,
                         elu1(fk.z) * 0.125f, elu1(fk.w) * 0.125f };
        us4 uk; uk.x = f2bf(kv4[0]); uk.y = f2bf(kv4[1]);
                uk.z = f2bf(kv4[2]); uk.w = f2bf(kv4[3]);
        *reinterpret_cast<us4*>(&kb[SWZ(r, c0)]) = uk;
        xpose4<16, 32>(kv4, lane);                   // -> col d=c0+g, rows rb..rb+3
        *reinterpret_cast<u64*>(&stk[SWZ(c0 + g, rb)]) = pack4bf(kv4);

        float4 fv = *reinterpret_cast<const float4*>(
            v + ((size_t)(b * SS + s0 + r) * HH + h) * DD + c0);
        float vv4[4] = { fv.x, fv.y, fv.z, fv.w };
        xpose4<16, 32>(vv4, lane);
        *reinterpret_cast<u64*>(&vT[SWZ(c0 + g, rb)]) = pack4bf(vv4);
    }

    const int lr    = lane & 15;
    const int lk    = (lane >> 4) * 8;
    const int mbase = wid * 16;
    const int crow  = (lane >> 4) * 4;

    // epilogue norm inputs: issue loads early, use at the end
    const float off = offset[h];
    float nv[4];
#pragma unroll
    for (int r = 0; r < 4; ++r) {
        const int s = s0 + mbase + crow + r;
        nv[r] = nrm[(size_t)(b * SS + s) * HH + h] + off;
    }

    __syncthreads();

    // ---- A2: chunk state S_c^T[t][d] = sum_s vT[t,s] * kT[d,s] ----
    f32x4 sc[4] = {};
#pragma unroll
    for (int kk = 0; kk < 2; ++kk) {
        short8 av = *reinterpret_cast<const short8*>(&vT[SWZ(mbase + lr, kk * 32 + lk)]);
#pragma unroll
        for (int nb = 0; nb < 4; ++nb) {
            short8 bk = *reinterpret_cast<const short8*>(&stk[SWZ(nb * 16 + lr, kk * 32 + lk)]);
            sc[nb] = __builtin_amdgcn_mfma_f32_16x16x32_bf16(av, bk, sc[nb], 0, 0, 0);
        }
    }

    // ---- B: publish aggregate image (agent-scope stores bypass local L2) ----
    u64* myAgg = aggWs + (size_t)blk * 1024;
#pragma unroll
    for (int nb = 0; nb < 4; ++nb) {
        float cv[4] = { sc[nb][0], sc[nb][1], sc[nb][2], sc[nb][3] };
        xpose4<1, 2>(cv, lane);                      // lane: row t=crow+(lane&3), 4 d-cols
        const int t  = mbase + crow + (lane & 3);
        const int d0 = nb * 16 + (lr & ~3);
        __hip_atomic_store(myAgg + (SWZ(t, d0) >> 2), pack4bf(cv),
                           __ATOMIC_RELAXED, __HIP_MEMORY_SCOPE_AGENT);
    }

    // ---- scores = Q K^T (independent of state; runs while stores drain) ----
    f32x4 as4[4] = {};
#pragma unroll
    for (int kk = 0; kk < 2; ++kk) {
        short8 aq = *reinterpret_cast<const short8*>(&qb[SWZ(mbase + lr, kk * 32 + lk)]);
#pragma unroll
        for (int nb = 0; nb < 4; ++nb) {
            short8 bk = *reinterpret_cast<const short8*>(&kb[SWZ(nb * 16 + lr, kk * 32 + lk)]);
            as4[nb] = __builtin_amdgcn_mfma_f32_16x16x32_bf16(aq, bk, as4[nb], 0, 0, 0);
        }
    }

    __syncthreads();   // all stk/kb reads done; all agg stores drained (vmcnt)
    if (tid == 0) {
        __threadfence();   // belt-and-braces agent release of the image
        __hip_atomic_store(&flags[blk], 1, __ATOMIC_RELEASE, __HIP_MEMORY_SCOPE_AGENT);
    }

    // ---- causal-masked scores overlay kb (wave-local rows; ds-ordered) ----
    // issued before lookback so the ds_writes hide under the L3 loads
#pragma unroll
    for (int nb = 0; nb < 4; ++nb) {
#pragma unroll
        for (int r = 0; r < 4; ++r) {
            const int s_loc = mbase + crow + r;
            const int s2    = nb * 16 + lr;
            const float val = (s2 <= s_loc) ? as4[nb][r] : 0.f;
            kb[SWZ(s_loc, s2)] = f2bf(val);
        }
    }

    // ---- C: lookback — fp32 sum of predecessors' aggregates ----
    float run[16] = {};
    if (c > 0) {
        // vector poll: lane j watches chunk j's flag
        for (;;) {
            int f = 1;
            if (lane < c)
                f = __hip_atomic_load(&flags[lane * BHH + bh],
                                      __ATOMIC_ACQUIRE, __HIP_MEMORY_SCOPE_AGENT);
            if (__ballot(f == 1) == ~0ull) break;
            __builtin_amdgcn_s_sleep(2);
        }
        for (int j = 0; j < c; ++j) {
            const u64* src = aggWs + (size_t)(j * BHH + bh) * 1024 + tid * 4;
#pragma unroll
            for (int w2 = 0; w2 < 4; ++w2) {
                u64 x = __hip_atomic_load(&src[w2],
                                          __ATOMIC_RELAXED, __HIP_MEMORY_SCOPE_AGENT);
                run[w2 * 4 + 0] += bf2f((unsigned short)(x));
                run[w2 * 4 + 1] += bf2f((unsigned short)(x >> 16));
                run[w2 * 4 + 2] += bf2f((unsigned short)(x >> 32));
                run[w2 * 4 + 3] += bf2f((unsigned short)(x >> 48));
            }
        }
    }

    // ---- overlay stk with S_excl^T image (bf16) ----
    u64* stk64 = reinterpret_cast<u64*>(stk);
#pragma unroll
    for (int w2 = 0; w2 < 4; ++w2) {
        float cv[4] = { run[w2 * 4 + 0], run[w2 * 4 + 1],
                        run[w2 * 4 + 2], run[w2 * 4 + 3] };
        stk64[tid * 4 + w2] = pack4bf(cv);
    }
    __syncthreads();   // S_excl image complete (cross-wave reads follow)

    // ---- D: O = Q @ S_excl + As @ V ----
    f32x4 acc[4] = {};
#pragma unroll
    for (int kk = 0; kk < 2; ++kk) {
        short8 aq = *reinterpret_cast<const short8*>(&qb[SWZ(mbase + lr, kk * 32 + lk)]);
#pragma unroll
        for (int nb = 0; nb < 4; ++nb) {
            short8 bs = *reinterpret_cast<const short8*>(&stk[SWZ(nb * 16 + lr, kk * 32 + lk)]);
            acc[nb] = __builtin_amdgcn_mfma_f32_16x16x32_bf16(aq, bs, acc[nb], 0, 0, 0);
        }
    }
#pragma unroll
    for (int kk = 0; kk < 2; ++kk) {
        short8 aa = *reinterpret_cast<const short8*>(&kb[SWZ(mbase + lr, kk * 32 + lk)]);
#pragma unroll
        for (int nb = 0; nb < 4; ++nb) {
            short8 bv = *reinterpret_cast<const short8*>(&vT[SWZ(nb * 16 + lr, kk * 32 + lk)]);
            acc[nb] = __builtin_amdgcn_mfma_f32_16x16x32_bf16(aa, bv, acc[nb], 0, 0, 0);
        }
    }

    // ---- epilogue: norm = 1/(1+exp(n+off)); store fp32 ----
#pragma unroll
    for (int r = 0; r < 4; ++r) nv[r] = 1.f / (1.f + __expf(nv[r]));
#pragma unroll
    for (int nb = 0; nb < 4; ++nb) {
#pragma unroll
        for (int r = 0; r < 4; ++r) {
            const int s = s0 + mbase + crow + r;
            out[((size_t)(b * SS + s) * HH + h) * DD + nb * 16 + lr] = acc[nb][r] * nv[r];
        }
    }
}

// ---------------------------------------------------------------------------
extern "C" void kernel_launch(void* const* d_in, const int* in_sizes, int n_in,
                              void* d_out, int out_size, void* d_ws, size_t ws_size,
                              hipStream_t stream) {
    const float* qk     = (const float*)d_in[0];
    const float* v      = (const float*)d_in[1];
    const float* nrm    = (const float*)d_in[2];
    const float* offset = (const float*)d_in[3];
    float* out = (float*)d_out;

    u64* aggWs = (u64*)d_ws;                         // 1024 blocks x 8KB = 8.39 MB
    int* flags = (int*)(aggWs + (size_t)BHH * NCK * 1024);

    fused_kernel<<<dim3(BHH * NCK), dim3(256), 0, stream>>>(
        qk, v, nrm, offset, aggWs, flags, out);
}

// Round 8
// 118.175 us; speedup vs baseline: 1.8682x; 1.8682x over previous
//
#include <hip/hip_runtime.h>
#include <cstdint>

// Problem constants (B,S,H,D from reference)
#define BB 4
#define SS 2048
#define HH 8
#define DD 64
#define CC 64          // chunk length
#define NCK (SS/CC)    // 32 chunks
#define BHH (BB*HH)    // 32

typedef __attribute__((ext_vector_type(8))) short  short8;   // 8 bf16 (MFMA A/B frag)
typedef __attribute__((ext_vector_type(4))) float  f32x4;    // MFMA C/D frag
typedef __attribute__((ext_vector_type(4))) unsigned short us4;
typedef unsigned long long u64;

__device__ __forceinline__ float elu1(float x) {
    return x > 0.f ? x + 1.f : __expf(x);
}
// fp32 -> bf16 RNE
__device__ __forceinline__ unsigned short f2bf(float f) {
    unsigned int u = __float_as_uint(f);
    u += 0x7FFFu + ((u >> 16) & 1u);
    return (unsigned short)(u >> 16);
}
__device__ __forceinline__ float bf2f(unsigned short h) {
    return __uint_as_float(((unsigned int)h) << 16);
}
// XOR swizzle for [64][64] bf16 tiles (rows 128B). ws tiles store the exact
// swizzled LDS byte image (element-wise ops are layout-agnostic).
#define SWZ(r,c) ((r) * DD + ((c) ^ (((r) & 7) << 3)))

// 4x4 lane-transpose across lane groups M0,M1 (4 shfl_xor).
template<int M0, int M1>
__device__ __forceinline__ void xpose4(float v[4], int lane) {
    {
        const bool hi = (lane & M0) != 0;
        float x0 = hi ? v[0] : v[1];
        float x1 = hi ? v[2] : v[3];
        float r0 = __shfl_xor(x0, M0);
        float r1 = __shfl_xor(x1, M0);
        if (hi) { v[0] = r0; v[2] = r1; } else { v[1] = r0; v[3] = r1; }
    }
    {
        const bool hi = (lane & M1) != 0;
        float x0 = hi ? v[0] : v[2];
        float x1 = hi ? v[1] : v[3];
        float r0 = __shfl_xor(x0, M1);
        float r1 = __shfl_xor(x1, M1);
        if (hi) { v[0] = r0; v[1] = r1; } else { v[2] = r0; v[3] = r1; }
    }
}

__device__ __forceinline__ u64 pack4bf(const float v[4]) {
    u64 r;
    r  = (u64)f2bf(v[0]);
    r |= (u64)f2bf(v[1]) << 16;
    r |= (u64)f2bf(v[2]) << 32;
    r |= (u64)f2bf(v[3]) << 48;
    return r;
}

// ---------------------------------------------------------------------------
// Kernel 1: per-chunk transform + chunk state.
// Stages k (elu*scale) and v; builds K^T/V^T swizzled bf16 LDS tiles via
// 4x4 lane transposes; MFMA S_c^T[t][d] = sum_s vT[t,s]*kT[d,s]; writes
// bf16 byte images: kb[s2][d] (kws), V^T (vtws), S_c (Sws).
// grid = 1024, 256 thr, LDS 16 KB. Kernel boundary = coherence for K2.
// ---------------------------------------------------------------------------
__global__ __launch_bounds__(256) void state_kernel(
    const float* __restrict__ qk, const float* __restrict__ v,
    unsigned short* __restrict__ kws, unsigned short* __restrict__ vtws,
    u64* __restrict__ Sws)
{
    const int blk = blockIdx.x;
    const int bh = blk / NCK, c = blk % NCK;
    const int b = bh / HH, h = bh % HH;
    const int s0 = c * CC;

    __shared__ __align__(16) unsigned short kT[CC * DD];   // K^T [d][s] swz
    __shared__ __align__(16) unsigned short vT[CC * DD];   // V^T [t][s] swz

    const int tid = threadIdx.x, lane = tid & 63;

#pragma unroll
    for (int iter = 0; iter < 4; ++iter) {
        const int it = iter * 256 + tid;
        const int r = it >> 4, c0 = (it & 15) * 4;   // row s=r, cols c0..c0+3
        const int g = lane >> 4;                     // row within 4x4 block
        const int rb = r - g;                        // 4-aligned block row base

        const size_t krow = (((size_t)(b * SS + s0 + r) * 2 + 1) * HH + h) * DD;

        float4 fk = *reinterpret_cast<const float4*>(qk + krow + c0);
        float kv4[4] = { elu1(fk.x) * 0.125f, elu1(fk.y) * 0.125f,
                         elu1(fk.z) * 0.125f, elu1(fk.w) * 0.125f };
        us4 uk; uk.x = f2bf(kv4[0]); uk.y = f2bf(kv4[1]);
                uk.z = f2bf(kv4[2]); uk.w = f2bf(kv4[3]);
        *reinterpret_cast<us4*>(kws + (size_t)blk * 4096 + SWZ(r, c0)) = uk;
        xpose4<16, 32>(kv4, lane);                   // -> col d=c0+g, rows rb..rb+3
        *reinterpret_cast<u64*>(&kT[SWZ(c0 + g, rb)]) = pack4bf(kv4);

        float4 fv = *reinterpret_cast<const float4*>(
            v + ((size_t)(b * SS + s0 + r) * HH + h) * DD + c0);
        float vv4[4] = { fv.x, fv.y, fv.z, fv.w };
        xpose4<16, 32>(vv4, lane);
        *reinterpret_cast<u64*>(&vT[SWZ(c0 + g, rb)]) = pack4bf(vv4);
    }
    __syncthreads();

    // dump V^T byte image (linear read of swizzled LDS -> ws stays swizzled)
#pragma unroll
    for (int j = 0; j < 2; ++j) {
        const int slot = j * 256 + tid;
        *reinterpret_cast<short8*>(vtws + (size_t)blk * 4096 + slot * 8) =
            *reinterpret_cast<const short8*>(&vT[slot * 8]);
    }

    // MFMA: S_c^T[t][d] = sum_s vT[t,s] * kT[d,s]
    const int lr = lane & 15, lk = (lane >> 4) * 8;
    const int wid = tid >> 6, mbase = wid * 16;
    f32x4 sc[4] = {};
#pragma unroll
    for (int kk = 0; kk < 2; ++kk) {
        short8 a = *reinterpret_cast<const short8*>(&vT[SWZ(mbase + lr, kk * 32 + lk)]);
#pragma unroll
        for (int nb = 0; nb < 4; ++nb) {
            short8 bk = *reinterpret_cast<const short8*>(&kT[SWZ(nb * 16 + lr, kk * 32 + lk)]);
            sc[nb] = __builtin_amdgcn_mfma_f32_16x16x32_bf16(a, bk, sc[nb], 0, 0, 0);
        }
    }
    // S_c image write (swizzled [t][d] u64 image)
    const int crow = (lane >> 4) * 4;
#pragma unroll
    for (int nb = 0; nb < 4; ++nb) {
        float cv[4] = { sc[nb][0], sc[nb][1], sc[nb][2], sc[nb][3] };
        xpose4<1, 2>(cv, lane);                      // lane: row t=crow+(lane&3), 4 d-cols
        const int t  = mbase + crow + (lane & 3);
        const int d0 = nb * 16 + (lr & ~3);
        Sws[(size_t)blk * 1024 + (SWZ(t, d0) >> 2)] = pack4bf(cv);
    }
}

// ---------------------------------------------------------------------------
// Kernel 2: output + in-block prefix.
// Stages kb/vT via global_load_lds (verbatim byte images), q from fp32;
// prefix = plain coalesced b64 loads of the c predecessor S images
// (L2/L3-resident, 8.4MB total) summed in fp32; then
// O = Q@S_excl + causal(QK^T)@V ; out = norm * O.
// grid = 1024, 256 thr, LDS 32 KB.
// ---------------------------------------------------------------------------
__global__ __launch_bounds__(256, 4) void out_kernel(
    const float* __restrict__ qk, const float* __restrict__ nrm,
    const float* __restrict__ offset,
    const unsigned short* __restrict__ kws, const unsigned short* __restrict__ vtws,
    const u64* __restrict__ Sws, float* __restrict__ out)
{
    const int blk = blockIdx.x;
    const int bh = blk / NCK, c = blk % NCK;
    const int b = bh / HH, h = bh % HH;
    const int s0 = c * CC;

    __shared__ __align__(16) unsigned short qb[CC * DD];   // Q  [s][d]  swz
    __shared__ __align__(16) unsigned short kb[CC * DD];   // K  [s2][d] swz -> As[s][s2]
    __shared__ __align__(16) unsigned short vT[CC * DD];   // V^T[t][s]  swz
    __shared__ __align__(16) unsigned short stk[CC * DD];  // S_excl^T[t][d] swz

    const int tid = threadIdx.x, lane = tid & 63;
    const int wid = tid >> 6;

    // ---- async stage kb, vT (byte images; no VGPR round trip) ----
    {
        const unsigned short* gsrc[2] = { kws + (size_t)blk * 4096,
                                          vtws + (size_t)blk * 4096 };
        unsigned short* ldst[2] = { kb, vT };
#pragma unroll
        for (int bu = 0; bu < 2; ++bu) {
#pragma unroll
            for (int j = 0; j < 2; ++j) {
                const unsigned short* gp = gsrc[bu] + (size_t)(j * 256 + tid) * 8;
                __builtin_amdgcn_global_load_lds(
                    (const __attribute__((address_space(1))) void*)gp,
                    (__attribute__((address_space(3))) void*)(ldst[bu] + j * 2048 + wid * 512),
                    16, 0, 0);
            }
        }
    }

    // ---- stage q (fp32 -> elu1 -> bf16, swizzled) ----
#pragma unroll
    for (int iter = 0; iter < 4; ++iter) {
        const int it = iter * 256 + tid;
        const int r = it >> 4, c0 = (it & 15) * 4;
        const size_t qrow = (((size_t)(b * SS + s0 + r) * 2 + 0) * HH + h) * DD;
        float4 fq = *reinterpret_cast<const float4*>(qk + qrow + c0);
        us4 uq; uq.x = f2bf(elu1(fq.x)); uq.y = f2bf(elu1(fq.y));
                uq.z = f2bf(elu1(fq.z)); uq.w = f2bf(elu1(fq.w));
        *reinterpret_cast<us4*>(&qb[SWZ(r, c0)]) = uq;
    }

    const int lr    = lane & 15;
    const int lk    = (lane >> 4) * 8;
    const int mbase = wid * 16;
    const int crow  = (lane >> 4) * 4;

    // epilogue norm inputs (issue early)
    const float off = offset[h];
    float nv[4];
#pragma unroll
    for (int r = 0; r < 4; ++r) {
        const int s = s0 + mbase + crow + r;
        nv[r] = nrm[(size_t)(b * SS + s) * HH + h] + off;
    }

    // ---- prefix: fp32 sum of predecessor S images (plain coalesced loads) ----
    float run[16] = {};
    {
        const u64* base = Sws + (size_t)bh * NCK * 1024 + (size_t)tid * 4;
        int j = 0;
        for (; j + 2 <= c; j += 2) {
            const u64* s0p = base + (size_t)j * 1024;
            const u64* s1p = s0p + 1024;
            u64 x0[4], x1[4];
#pragma unroll
            for (int w2 = 0; w2 < 4; ++w2) { x0[w2] = s0p[w2]; x1[w2] = s1p[w2]; }
#pragma unroll
            for (int w2 = 0; w2 < 4; ++w2) {
                run[w2 * 4 + 0] += bf2f((unsigned short)(x0[w2]))       + bf2f((unsigned short)(x1[w2]));
                run[w2 * 4 + 1] += bf2f((unsigned short)(x0[w2] >> 16)) + bf2f((unsigned short)(x1[w2] >> 16));
                run[w2 * 4 + 2] += bf2f((unsigned short)(x0[w2] >> 32)) + bf2f((unsigned short)(x1[w2] >> 32));
                run[w2 * 4 + 3] += bf2f((unsigned short)(x0[w2] >> 48)) + bf2f((unsigned short)(x1[w2] >> 48));
            }
        }
        if (j < c) {
            const u64* s0p = base + (size_t)j * 1024;
#pragma unroll
            for (int w2 = 0; w2 < 4; ++w2) {
                u64 x = s0p[w2];
                run[w2 * 4 + 0] += bf2f((unsigned short)(x));
                run[w2 * 4 + 1] += bf2f((unsigned short)(x >> 16));
                run[w2 * 4 + 2] += bf2f((unsigned short)(x >> 32));
                run[w2 * 4 + 3] += bf2f((unsigned short)(x >> 48));
            }
        }
    }
    // S_excl^T bf16 image into stk
    u64* stk64 = reinterpret_cast<u64*>(stk);
#pragma unroll
    for (int w2 = 0; w2 < 4; ++w2) {
        float cv[4] = { run[w2 * 4 + 0], run[w2 * 4 + 1],
                        run[w2 * 4 + 2], run[w2 * 4 + 3] };
        stk64[(size_t)tid * 4 + w2] = pack4bf(cv);
    }

    __syncthreads();   // drains gload_lds (vmcnt) + all ds writes

    // ---- phase 1: O = Q@S_excl ; scores = Q K^T ----
    f32x4 acc[4] = {};
    f32x4 as4[4] = {};
#pragma unroll
    for (int kk = 0; kk < 2; ++kk) {
        short8 aq = *reinterpret_cast<const short8*>(&qb[SWZ(mbase + lr, kk * 32 + lk)]);
#pragma unroll
        for (int nb = 0; nb < 4; ++nb) {
            short8 bs = *reinterpret_cast<const short8*>(&stk[SWZ(nb * 16 + lr, kk * 32 + lk)]);
            acc[nb] = __builtin_amdgcn_mfma_f32_16x16x32_bf16(aq, bs, acc[nb], 0, 0, 0);
            short8 bk = *reinterpret_cast<const short8*>(&kb[SWZ(nb * 16 + lr, kk * 32 + lk)]);
            as4[nb] = __builtin_amdgcn_mfma_f32_16x16x32_bf16(aq, bk, as4[nb], 0, 0, 0);
        }
    }
    __syncthreads();   // all waves done reading kb before overlay

    // ---- causal-masked scores into kb as As[s][s2] (wave-local rows) ----
#pragma unroll
    for (int nb = 0; nb < 4; ++nb) {
#pragma unroll
        for (int r = 0; r < 4; ++r) {
            const int s_loc = mbase + crow + r;
            const int s2    = nb * 16 + lr;
            const float val = (s2 <= s_loc) ? as4[nb][r] : 0.f;
            kb[SWZ(s_loc, s2)] = f2bf(val);
        }
    }
    // reads below are same-wave rows; compiler inserts lgkmcnt ordering

    // ---- phase 2: O += As @ V ----
#pragma unroll
    for (int kk = 0; kk < 2; ++kk) {
        short8 aa = *reinterpret_cast<const short8*>(&kb[SWZ(mbase + lr, kk * 32 + lk)]);
#pragma unroll
        for (int nb = 0; nb < 4; ++nb) {
            short8 bv = *reinterpret_cast<const short8*>(&vT[SWZ(nb * 16 + lr, kk * 32 + lk)]);
            acc[nb] = __builtin_amdgcn_mfma_f32_16x16x32_bf16(aa, bv, acc[nb], 0, 0, 0);
        }
    }

    // ---- epilogue ----
#pragma unroll
    for (int r = 0; r < 4; ++r) nv[r] = 1.f / (1.f + __expf(nv[r]));
#pragma unroll
    for (int nb = 0; nb < 4; ++nb) {
#pragma unroll
        for (int r = 0; r < 4; ++r) {
            const int s = s0 + mbase + crow + r;
            out[((size_t)(b * SS + s) * HH + h) * DD + nb * 16 + lr] = acc[nb][r] * nv[r];
        }
    }
}

// ---------------------------------------------------------------------------
extern "C" void kernel_launch(void* const* d_in, const int* in_sizes, int n_in,
                              void* d_out, int out_size, void* d_ws, size_t ws_size,
                              hipStream_t stream) {
    const float* qk     = (const float*)d_in[0];
    const float* v      = (const float*)d_in[1];
    const float* nrm    = (const float*)d_in[2];
    const float* offset = (const float*)d_in[3];
    float* out = (float*)d_out;

    const size_t TILE = (size_t)BHH * NCK * 4096;    // bf16 elems per buffer
    unsigned short* kws  = (unsigned short*)d_ws;    // 8.39 MB
    unsigned short* vtws = kws + TILE;               // 8.39 MB
    u64* Sws = (u64*)(vtws + TILE);                  // 8.39 MB (u64 image)

    state_kernel<<<dim3(BHH * NCK), dim3(256), 0, stream>>>(qk, v, kws, vtws, Sws);
    out_kernel<<<dim3(BHH * NCK), dim3(256), 0, stream>>>(qk, nrm, offset, kws, vtws, Sws, out);
}